// Round 14
// baseline (343.470 us; speedup 1.0000x reference)
//
#include <hip/hip_runtime.h>
#include <math.h>

#define B_ 64
#define S_ 64
#define U_ 16
#define EMB_ 10
#define D_ 34
#define DD_ 3
#define FF_ 4
#define NL_ 4

typedef float v2f __attribute__((ext_vector_type(2)));

// ---------------------------------------------------------------------------
// Kernel A: encoder — R13 structure + FF1 computed redundantly per-wave in
// registers (FF2 only reads lane-local values) -> deletes the ffh LDS array,
// the FF1->FF2 barrier, and the 4-wave FF1 serialization.
// ---------------------------------------------------------------------------
__global__ __launch_bounds__(512) void enc_kernel(
    const float* __restrict__ src, const float* __restrict__ wemb,
    const float* __restrict__ semb,
    const float* __restrict__ qkv_w, const float* __restrict__ qkv_b,
    const float* __restrict__ out_w, const float* __restrict__ out_b,
    const float* __restrict__ ln1_w, const float* __restrict__ ln1_b,
    const float* __restrict__ lin1_w, const float* __restrict__ lin1_b,
    const float* __restrict__ lin2_w, const float* __restrict__ lin2_b,
    const float* __restrict__ ln2_w, const float* __restrict__ ln2_b,
    const float* __restrict__ norm_w, const float* __restrict__ norm_b,
    const float* __restrict__ eo_w, const float* __restrict__ eo_b,
    float* __restrict__ mem, float* __restrict__ out)
{
    const int b = blockIdx.x;
    const int tid = threadIdx.x;
    const int wv_ = tid >> 6;
    const int lane = tid & 63;

    __shared__ float xs[S_][D_ + 1];
    __shared__ float tmp[S_][D_ + 1];
    __shared__ float att[S_][D_ + 1];
    __shared__ __align__(16) float qsh[2][S_][21];
    __shared__ __align__(16) float ksh[2][S_][20];
    __shared__ __align__(16) float vsh[2][S_][20];
    __shared__ float pacc[4][128][19];

    const float rs17 = 0.24253562503633297f;
    const float negln = -logf(10000.0f) / (float)D_;

    // ---- embed + positional encoding
    #pragma unroll
    for (int rr = 0; rr < 5; ++rr) {
        int idx = tid + rr * 512;
        if (idx < S_ * D_) {
            int pos = idx / D_, d = idx % D_;
            float v;
            if (d < U_ - 2) {
                v = src[(b * S_ + pos) * U_ + d];
            } else if (d < U_ - 2 + EMB_) {
                int wi = (int)src[(b * S_ + pos) * U_ + (U_ - 2)];
                v = wemb[wi * EMB_ + (d - (U_ - 2))];
            } else {
                int si = (int)src[(b * S_ + pos) * U_ + (U_ - 1)];
                v = semb[si * EMB_ + (d - (U_ - 2 + EMB_))];
            }
            int k = d >> 1;
            float div = __expf((float)(2 * k) * negln);
            float ang = (float)b * div;
            v += (d & 1) ? __cosf(ang) : __sinf(ang);
            xs[pos][d] = v;
        }
    }
    __syncthreads();

    for (int l = 0; l < NL_; ++l) {
        const float* Wq = qkv_w + l * 3 * D_ * D_;
        const float* Bq = qkv_b + l * 3 * D_;

        // ---- qkv: lane = pos; wave owns rows r = wv_ + 8k; pk_fma dot
        {
            v2f xr2[17];
            #pragma unroll
            for (int d2 = 0; d2 < 17; ++d2) {
                v2f t; t.x = xs[lane][2 * d2]; t.y = xs[lane][2 * d2 + 1];
                xr2[d2] = t;
            }
            #pragma unroll
            for (int rb = 0; rb < 13; ++rb) {
                int r = wv_ + (rb << 3);
                if (r < 3 * D_) {
                    int ru = __builtin_amdgcn_readfirstlane(r);
                    const v2f* w2 = (const v2f*)(Wq + ru * D_);
                    v2f a2; a2.x = Bq[ru]; a2.y = 0.f;
                    #pragma unroll
                    for (int d2 = 0; d2 < 17; ++d2)
                        a2 = __builtin_elementwise_fma(xr2[d2], w2[d2], a2);
                    float acc = a2.x + a2.y;
                    if (ru < D_)          { int h = (ru >= 17), dd = ru - h * 17; qsh[h][lane][dd] = acc; }
                    else if (ru < 2 * D_) { int rr2 = ru - D_;     int h = (rr2 >= 17), dd = rr2 - h * 17; ksh[h][lane][dd] = acc; }
                    else                  { int rr2 = ru - 2 * D_; int h = (rr2 >= 17), dd = rr2 - h * 17; vsh[h][lane][dd] = acc; }
                }
            }
        }
        __syncthreads();

        // ---- attention, 4-way key-parallel
        {
            int c = tid >> 7, hq = tid & 127;
            int h = hq >> 6, qi = hq & 63;
            float qv[17], acc[17];
            #pragma unroll
            for (int d = 0; d < 17; ++d) { qv[d] = qsh[h][qi][d]; acc[d] = 0.f; }
            float ssum = 0.f;
            int j0 = c * 16;
            #pragma unroll 4
            for (int jj = 0; jj < 16; ++jj) {
                int j = j0 + jj;
                const float4* kr = (const float4*)ksh[h][j];
                const float4* vr = (const float4*)vsh[h][j];
                float4 k0 = kr[0], k1 = kr[1], k2 = kr[2], k3 = kr[3];
                float  k16 = ksh[h][j][16];
                float4 v0 = vr[0], v1 = vr[1], v2 = vr[2], v3 = vr[3];
                float  v16 = vsh[h][j][16];
                float sE = qv[0]*k0.x + qv[2]*k0.z + qv[4]*k1.x + qv[6]*k1.z +
                           qv[8]*k2.x + qv[10]*k2.z + qv[12]*k3.x + qv[14]*k3.z;
                float sO = qv[1]*k0.y + qv[3]*k0.w + qv[5]*k1.y + qv[7]*k1.w +
                           qv[9]*k2.y + qv[11]*k2.w + qv[13]*k3.y + qv[15]*k3.w;
                float sc = sE + sO + qv[16]*k16;
                float e = __expf(sc * rs17);
                ssum += e;
                acc[0] += e*v0.x;  acc[1] += e*v0.y;  acc[2] += e*v0.z;  acc[3] += e*v0.w;
                acc[4] += e*v1.x;  acc[5] += e*v1.y;  acc[6] += e*v1.z;  acc[7] += e*v1.w;
                acc[8] += e*v2.x;  acc[9] += e*v2.y;  acc[10] += e*v2.z; acc[11] += e*v2.w;
                acc[12] += e*v3.x; acc[13] += e*v3.y; acc[14] += e*v3.z; acc[15] += e*v3.w;
                acc[16] += e*v16;
            }
            #pragma unroll
            for (int d = 0; d < 17; ++d) pacc[c][hq][d] = acc[d];
            pacc[c][hq][17] = ssum;
        }
        __syncthreads();

        if (tid < 128) {
            int h = tid >> 6, qi = tid & 63;
            int off = h * 17;
            float ssum = pacc[0][tid][17] + pacc[1][tid][17] +
                         pacc[2][tid][17] + pacc[3][tid][17];
            float inv = 1.f / ssum;
            #pragma unroll
            for (int d = 0; d < 17; ++d)
                att[qi][off + d] = (pacc[0][tid][d] + pacc[1][tid][d] +
                                    pacc[2][tid][d] + pacc[3][tid][d]) * inv;
        }
        __syncthreads();

        // ---- out proj + residual (pk_fma)
        {
            v2f ar2[17];
            #pragma unroll
            for (int d2 = 0; d2 < 17; ++d2) {
                v2f t; t.x = att[lane][2 * d2]; t.y = att[lane][2 * d2 + 1];
                ar2[d2] = t;
            }
            const float* Wo = out_w + l * D_ * D_;
            const float* Bo = out_b + l * D_;
            #pragma unroll
            for (int rb = 0; rb < 5; ++rb) {
                int d = wv_ + (rb << 3);
                if (d < D_) {
                    int du = __builtin_amdgcn_readfirstlane(d);
                    const v2f* w2 = (const v2f*)(Wo + du * D_);
                    v2f a2; a2.x = Bo[du]; a2.y = 0.f;
                    #pragma unroll
                    for (int d2 = 0; d2 < 17; ++d2)
                        a2 = __builtin_elementwise_fma(ar2[d2], w2[d2], a2);
                    tmp[lane][du] = xs[lane][du] + a2.x + a2.y;
                }
            }
        }
        __syncthreads();

        // ---- LN1: 8 threads/row, shfl_xor(8) reduction
        {
            int row = tid >> 3, sub = tid & 7;
            float s = 0.f, sq = 0.f;
            #pragma unroll
            for (int d = sub; d < D_; d += 8) { float t = tmp[row][d]; s += t; sq = fmaf(t, t, sq); }
            #pragma unroll
            for (int m = 1; m < 8; m <<= 1) { s += __shfl_xor(s, m, 8); sq += __shfl_xor(sq, m, 8); }
            float mu = s * (1.0f / D_);
            float var = fmaf(sq, 1.0f / D_, -mu * mu);
            float rstd = rsqrtf(var + 1e-5f);
            #pragma unroll
            for (int d = sub; d < D_; d += 8)
                xs[row][d] = (tmp[row][d] - mu) * rstd * ln1_w[l * D_ + d] + ln1_b[l * D_ + d];
        }
        __syncthreads();

        // ---- FF1 in registers (redundant per wave; FF2 only needs
        // lane-local values) + FF2 + residual — one barrier saved
        {
            v2f x2[17];
            #pragma unroll
            for (int d2 = 0; d2 < 17; ++d2) {
                v2f t; t.x = xs[lane][2 * d2]; t.y = xs[lane][2 * d2 + 1];
                x2[d2] = t;
            }
            float hreg[4];
            #pragma unroll
            for (int f = 0; f < 4; ++f) {
                const v2f* w2 = (const v2f*)(lin1_w + l * FF_ * D_ + f * D_);
                v2f a2; a2.x = lin1_b[l * FF_ + f]; a2.y = 0.f;
                #pragma unroll
                for (int d2 = 0; d2 < 17; ++d2)
                    a2 = __builtin_elementwise_fma(x2[d2], w2[d2], a2);
                hreg[f] = fmaxf(a2.x + a2.y, 0.f);
            }
            const float* W2 = lin2_w + l * D_ * FF_;
            const float* B2 = lin2_b + l * D_;
            #pragma unroll
            for (int rb = 0; rb < 5; ++rb) {
                int d = wv_ + (rb << 3);
                if (d < D_) {
                    int du = __builtin_amdgcn_readfirstlane(d);
                    const float* wrow = W2 + du * FF_;
                    float acc = fmaf(hreg[0], wrow[0], fmaf(hreg[1], wrow[1],
                                fmaf(hreg[2], wrow[2], fmaf(hreg[3], wrow[3], B2[du]))));
                    tmp[lane][du] = xs[lane][du] + acc;
                }
            }
        }
        __syncthreads();

        // ---- LN2: 8 threads/row
        {
            int row = tid >> 3, sub = tid & 7;
            float s = 0.f, sq = 0.f;
            #pragma unroll
            for (int d = sub; d < D_; d += 8) { float t = tmp[row][d]; s += t; sq = fmaf(t, t, sq); }
            #pragma unroll
            for (int m = 1; m < 8; m <<= 1) { s += __shfl_xor(s, m, 8); sq += __shfl_xor(sq, m, 8); }
            float mu = s * (1.0f / D_);
            float var = fmaf(sq, 1.0f / D_, -mu * mu);
            float rstd = rsqrtf(var + 1e-5f);
            #pragma unroll
            for (int d = sub; d < D_; d += 8)
                xs[row][d] = (tmp[row][d] - mu) * rstd * ln2_w[l * D_ + d] + ln2_b[l * D_ + d];
        }
        __syncthreads();
    }

    // ---- final LayerNorm: 8 threads/row
    {
        int row = tid >> 3, sub = tid & 7;
        float s = 0.f, sq = 0.f;
        #pragma unroll
        for (int d = sub; d < D_; d += 8) { float t = xs[row][d]; s += t; sq = fmaf(t, t, sq); }
        #pragma unroll
        for (int m = 1; m < 8; m <<= 1) { s += __shfl_xor(s, m, 8); sq += __shfl_xor(sq, m, 8); }
        float mu = s * (1.0f / D_);
        float var = fmaf(sq, 1.0f / D_, -mu * mu);
        float rstd = rsqrtf(var + 1e-5f);
        #pragma unroll
        for (int d = sub; d < D_; d += 8)
            tmp[row][d] = (xs[row][d] - mu) * rstd * norm_w[d] + norm_b[d];
    }
    __syncthreads();

    // ---- memory = x @ eo_w.T + eo_b : waves 0..2 (pk_fma), reads tmp
    if (wv_ < 3) {
        int ru = __builtin_amdgcn_readfirstlane(wv_);
        const v2f* w2 = (const v2f*)(eo_w + ru * D_);
        v2f a2; a2.x = eo_b[ru]; a2.y = 0.f;
        #pragma unroll
        for (int d2 = 0; d2 < 17; ++d2) {
            v2f t; t.x = tmp[lane][2 * d2]; t.y = tmp[lane][2 * d2 + 1];
            a2 = __builtin_elementwise_fma(t, w2[d2], a2);
        }
        mem[(b * S_ + lane) * DD_ + ru] = a2.x + a2.y;
    }

    if (tid < S_) {
        out[(b * S_ + tid) * 5 + 3] = src[(b * S_ + tid) * U_ + (U_ - 2)];
        out[(b * S_ + tid) * 5 + 4] = src[(b * S_ + tid) * U_ + (U_ - 1)];
    }
}

// ---------------------------------------------------------------------------
// Kernel B: decoder — EXACT R9/R12/R13 (measured 151.6-152.5 µs). FROZEN.
// ---------------------------------------------------------------------------
#define PIN(x) asm volatile("" : "+v"(x))

template <int CTRL>
__device__ __forceinline__ float dpp_add(float v) {
    int t = __builtin_amdgcn_update_dpp(0, __float_as_int(v), CTRL, 0xf, 0xf, true);
    return v + __int_as_float(t);
}

__device__ __forceinline__ float wave_sum_l63(float v) {
    v = dpp_add<0x111>(v);
    v = dpp_add<0x112>(v);
    v = dpp_add<0x114>(v);
    v = dpp_add<0x118>(v);
    v = dpp_add<0x142>(v);
    v = dpp_add<0x143>(v);
    return v;
}

__device__ __forceinline__ float bcast63(float v) {
    return __int_as_float(__builtin_amdgcn_readlane(__float_as_int(v), 63));
}

__device__ __forceinline__ void ln3e(float z0, float z1, float z2,
                                     float w0, float w1, float w2,
                                     float b0, float b1, float b2,
                                     float& o0, float& o1, float& o2) {
    float s1 = (z0 + z1) + z2;
    float s2 = fmaf(z0, z0, fmaf(z1, z1, z2 * z2));
    float mu = s1 * (1.0f / 3.0f);
    float vpe = fmaf(s2, (1.0f / 3.0f), fmaf(-mu, mu, 1e-5f));
    float rstd = __builtin_amdgcn_rsqf(vpe);
    o0 = fmaf(z0 - mu, rstd * w0, b0);
    o1 = fmaf(z1 - mu, rstd * w1, b1);
    o2 = fmaf(z2 - mu, rstd * w2, b2);
}

__global__ __launch_bounds__(64, 1) void dec_kernel(
    const float* __restrict__ mem,
    const float* __restrict__ sa_qkv_w, const float* __restrict__ sa_qkv_b,
    const float* __restrict__ sa_out_w, const float* __restrict__ sa_out_b,
    const float* __restrict__ gln1_w, const float* __restrict__ gln1_b,
    const float* __restrict__ ca_qkv_w, const float* __restrict__ ca_qkv_b,
    const float* __restrict__ ca_out_w, const float* __restrict__ ca_out_b,
    const float* __restrict__ gln2_w, const float* __restrict__ gln2_b,
    const float* __restrict__ l1_w, const float* __restrict__ l1_b,
    const float* __restrict__ l2_w, const float* __restrict__ l2_b,
    const float* __restrict__ gln3_w, const float* __restrict__ gln3_b,
    float* __restrict__ out)
{
    const int b = blockIdx.x;
    const int lane = threadIdx.x;
    const float LOG2E = 1.4426950408889634f;
    const float rs3 = 0.5773502691896258f;
    const float QS = rs3 * LOG2E;   // score scale folded into weights, exp->exp2

    // ---- FF-tail weight stage (R5/R9 layout)
    __shared__ __align__(16) float fst[NL_][40];
    for (int t = lane; t < NL_ * 40; t += 64) {
        int l = t / 40, s = t % 40;
        float v = 0.f;
        if      (s < 12) v = l1_w[l * 12 + s];
        else if (s < 16) v = l1_b[l * 4 + (s - 12)];
        else if (s < 28) v = l2_w[l * 12 + (s - 16)];
        else if (s < 31) v = l2_b[l * 3 + (s - 28)];
        else if (s < 34) v = gln3_w[l * 3 + (s - 31)];
        else if (s < 37) v = gln3_b[l * 3 + (s - 34)];
        fst[l][s] = v;
    }
    __syncthreads();

    // ---- persistent pinned weights (R5 set, q rows scaled by QS)
    float Wsq[NL_][9][3], Bsq[NL_][9];
    float Wso[NL_][3][3], Bso[NL_][3];
    float N1w[NL_][3], N1b[NL_][3];
    float Wcq[NL_][3][3], Bcq[NL_][3];
    float Wco[NL_][3][3], Bco[NL_][3];
    float N2w[NL_][3], N2b[NL_][3];

    #pragma unroll
    for (int l = 0; l < NL_; ++l) {
        #pragma unroll
        for (int r = 0; r < 9; ++r) {
            float sc = (r < 3) ? QS : 1.0f;
            Bsq[l][r] = sa_qkv_b[l * 9 + r] * sc;
            #pragma unroll
            for (int c = 0; c < 3; ++c) Wsq[l][r][c] = sa_qkv_w[l * 27 + r * 3 + c] * sc;
        }
        #pragma unroll
        for (int r = 0; r < 3; ++r) {
            Bso[l][r] = sa_out_b[l * 3 + r];
            Bcq[l][r] = ca_qkv_b[l * 9 + r] * QS;
            Bco[l][r] = ca_out_b[l * 3 + r];
            N1w[l][r] = gln1_w[l * 3 + r];  N1b[l][r] = gln1_b[l * 3 + r];
            N2w[l][r] = gln2_w[l * 3 + r];  N2b[l][r] = gln2_b[l * 3 + r];
            #pragma unroll
            for (int c = 0; c < 3; ++c) {
                Wso[l][r][c] = sa_out_w[l * 9 + r * 3 + c];
                Wcq[l][r][c] = ca_qkv_w[l * 27 + r * 3 + c] * QS;
                Wco[l][r][c] = ca_out_w[l * 9 + r * 3 + c];
            }
        }
    }

    // ---- cross-attn K/V per lane (memory position = lane)
    float m0 = mem[(b * S_ + lane) * DD_ + 0];
    float m1 = mem[(b * S_ + lane) * DD_ + 1];
    float m2 = mem[(b * S_ + lane) * DD_ + 2];

    float ck[NL_][3], cv[NL_][3];
    #pragma unroll
    for (int l = 0; l < NL_; ++l) {
        #pragma unroll
        for (int r = 0; r < 3; ++r) {
            ck[l][r] = ca_qkv_w[l * 27 + (3 + r) * 3 + 0] * m0 +
                       ca_qkv_w[l * 27 + (3 + r) * 3 + 1] * m1 +
                       ca_qkv_w[l * 27 + (3 + r) * 3 + 2] * m2 + ca_qkv_b[l * 9 + 3 + r];
            cv[l][r] = ca_qkv_w[l * 27 + (6 + r) * 3 + 0] * m0 +
                       ca_qkv_w[l * 27 + (6 + r) * 3 + 1] * m1 +
                       ca_qkv_w[l * 27 + (6 + r) * 3 + 2] * m2 + ca_qkv_b[l * 9 + 6 + r];
        }
    }

    // ---- pin the chain-critical set (R5 set)
    #pragma unroll
    for (int l = 0; l < NL_; ++l) {
        #pragma unroll
        for (int r = 0; r < 9; ++r) {
            PIN(Bsq[l][r]);
            #pragma unroll
            for (int c = 0; c < 3; ++c) PIN(Wsq[l][r][c]);
        }
        #pragma unroll
        for (int r = 0; r < 3; ++r) {
            PIN(Bso[l][r]); PIN(Bcq[l][r]); PIN(Bco[l][r]);
            PIN(N1w[l][r]); PIN(N1b[l][r]); PIN(N2w[l][r]); PIN(N2b[l][r]);
            #pragma unroll
            for (int c = 0; c < 3; ++c) { PIN(Wso[l][r][c]); PIN(Wcq[l][r][c]); PIN(Wco[l][r][c]); }
        }
    }

    // self-attn KV cache: lane j owns position j
    float sk[NL_][3] = {{0.f}}, sv[NL_][3] = {{0.f}};

    if (lane < 3) out[(b * S_ + 0) * 5 + lane] = 0.f;

    float y0 = 0.f, y1 = 0.f, y2 = 0.f;

    for (int i = 0; i < S_ - 1; ++i) {
        float msa = (lane <= i) ? 0.f : -1.0e30f;   // causal mask, once/step
        #pragma unroll
        for (int l = 0; l < NL_; ++l) {
            // ---- FF-tail weights: LDS reads at layer top, PINned (R9 scheme)
            float wv[40];
            {
                const float4* fp = (const float4*)fst[l];
                #pragma unroll
                for (int k = 0; k < 10; ++k) {
                    float4 t4 = fp[k];
                    wv[4 * k + 0] = t4.x; wv[4 * k + 1] = t4.y;
                    wv[4 * k + 2] = t4.z; wv[4 * k + 3] = t4.w;
                }
                #pragma unroll
                for (int k = 0; k < 37; ++k) PIN(wv[k]);
            }

            // ---- causal self-attention (q pre-scaled by QS; mask in fma)
            float q[3], kn[3], vn[3];
            #pragma unroll
            for (int r = 0; r < 3; ++r) {
                q[r]  = fmaf(Wsq[l][r][0], y0, fmaf(Wsq[l][r][1], y1, fmaf(Wsq[l][r][2], y2, Bsq[l][r])));
                kn[r] = fmaf(Wsq[l][3 + r][0], y0, fmaf(Wsq[l][3 + r][1], y1, fmaf(Wsq[l][3 + r][2], y2, Bsq[l][3 + r])));
                vn[r] = fmaf(Wsq[l][6 + r][0], y0, fmaf(Wsq[l][6 + r][1], y1, fmaf(Wsq[l][6 + r][2], y2, Bsq[l][6 + r])));
            }
            if (lane == i) {
                #pragma unroll
                for (int r = 0; r < 3; ++r) { sk[l][r] = kn[r]; sv[l][r] = vn[r]; }
            }
            float sc = fmaf(q[0], sk[l][0], fmaf(q[1], sk[l][1], fmaf(q[2], sk[l][2], msa)));
            float e = __builtin_amdgcn_exp2f(sc);
            float es  = wave_sum_l63(e);
            float ev0 = wave_sum_l63(e * sv[l][0]);
            float ev1 = wave_sum_l63(e * sv[l][1]);
            float ev2 = wave_sum_l63(e * sv[l][2]);
            float inv = __builtin_amdgcn_rcpf(bcast63(es));
            float a0 = bcast63(ev0) * inv, a1 = bcast63(ev1) * inv, a2 = bcast63(ev2) * inv;
            float s0 = fmaf(Wso[l][0][0], a0, fmaf(Wso[l][0][1], a1, fmaf(Wso[l][0][2], a2, Bso[l][0])));
            float s1 = fmaf(Wso[l][1][0], a0, fmaf(Wso[l][1][1], a1, fmaf(Wso[l][1][2], a2, Bso[l][1])));
            float s2 = fmaf(Wso[l][2][0], a0, fmaf(Wso[l][2][1], a1, fmaf(Wso[l][2][2], a2, Bso[l][2])));
            ln3e(y0 + s0, y1 + s1, y2 + s2,
                 N1w[l][0], N1w[l][1], N1w[l][2], N1b[l][0], N1b[l][1], N1b[l][2],
                 y0, y1, y2);

            // ---- cross-attention (p pre-scaled by QS)
            float p0 = fmaf(Wcq[l][0][0], y0, fmaf(Wcq[l][0][1], y1, fmaf(Wcq[l][0][2], y2, Bcq[l][0])));
            float p1 = fmaf(Wcq[l][1][0], y0, fmaf(Wcq[l][1][1], y1, fmaf(Wcq[l][1][2], y2, Bcq[l][1])));
            float p2 = fmaf(Wcq[l][2][0], y0, fmaf(Wcq[l][2][1], y1, fmaf(Wcq[l][2][2], y2, Bcq[l][2])));
            float sc2 = fmaf(p0, ck[l][0], fmaf(p1, ck[l][1], p2 * ck[l][2]));
            float e2 = __builtin_amdgcn_exp2f(sc2);
            float cs  = wave_sum_l63(e2);
            float cw0 = wave_sum_l63(e2 * cv[l][0]);
            float cw1 = wave_sum_l63(e2 * cv[l][1]);
            float cw2 = wave_sum_l63(e2 * cv[l][2]);
            inv = __builtin_amdgcn_rcpf(bcast63(cs));
            a0 = bcast63(cw0) * inv; a1 = bcast63(cw1) * inv; a2 = bcast63(cw2) * inv;
            float c0 = fmaf(Wco[l][0][0], a0, fmaf(Wco[l][0][1], a1, fmaf(Wco[l][0][2], a2, Bco[l][0])));
            float c1 = fmaf(Wco[l][1][0], a0, fmaf(Wco[l][1][1], a1, fmaf(Wco[l][1][2], a2, Bco[l][1])));
            float c2 = fmaf(Wco[l][2][0], a0, fmaf(Wco[l][2][1], a1, fmaf(Wco[l][2][2], a2, Bco[l][2])));
            ln3e(y0 + c0, y1 + c1, y2 + c2,
                 N2w[l][0], N2w[l][1], N2w[l][2], N2b[l][0], N2b[l][1], N2b[l][2],
                 y0, y1, y2);

            // ---- feed-forward 3 -> 4 -> 3 (relu) from LDS-staged wv[]
            float h0 = fmaxf(fmaf(wv[0], y0, fmaf(wv[1],  y1, fmaf(wv[2],  y2, wv[12]))), 0.f);
            float h1 = fmaxf(fmaf(wv[3], y0, fmaf(wv[4],  y1, fmaf(wv[5],  y2, wv[13]))), 0.f);
            float h2 = fmaxf(fmaf(wv[6], y0, fmaf(wv[7],  y1, fmaf(wv[8],  y2, wv[14]))), 0.f);
            float h3 = fmaxf(fmaf(wv[9], y0, fmaf(wv[10], y1, fmaf(wv[11], y2, wv[15]))), 0.f);
            float f0 = fmaf(wv[16], h0, fmaf(wv[17], h1, fmaf(wv[18], h2, fmaf(wv[19], h3, wv[28]))));
            float f1 = fmaf(wv[20], h0, fmaf(wv[21], h1, fmaf(wv[22], h2, fmaf(wv[23], h3, wv[29]))));
            float f2 = fmaf(wv[24], h0, fmaf(wv[25], h1, fmaf(wv[26], h2, fmaf(wv[27], h3, wv[30]))));
            ln3e(y0 + f0, y1 + f1, y2 + f2,
                 wv[31], wv[32], wv[33], wv[34], wv[35], wv[36],
                 y0, y1, y2);
        }
        if (lane == 0) {
            out[(b * S_ + i + 1) * 5 + 0] = y0;
            out[(b * S_ + i + 1) * 5 + 1] = y1;
            out[(b * S_ + i + 1) * 5 + 2] = y2;
        }
    }
}

// ---------------------------------------------------------------------------
extern "C" void kernel_launch(void* const* d_in, const int* in_sizes, int n_in,
                              void* d_out, int out_size, void* d_ws, size_t ws_size,
                              hipStream_t stream) {
    const float* src  = (const float*)d_in[0];
    const float* wemb = (const float*)d_in[1];
    const float* semb = (const float*)d_in[2];

    float* mem = (float*)d_ws;           // [B,S,3] scratch
    float* out = (float*)d_out;          // [B,S,5]

    enc_kernel<<<B_, 512, 0, stream>>>(
        src, wemb, semb,
        (const float*)d_in[3],  (const float*)d_in[4],
        (const float*)d_in[5],  (const float*)d_in[6],
        (const float*)d_in[7],  (const float*)d_in[8],
        (const float*)d_in[9],  (const float*)d_in[10],
        (const float*)d_in[11], (const float*)d_in[12],
        (const float*)d_in[13], (const float*)d_in[14],
        (const float*)d_in[15], (const float*)d_in[16],
        (const float*)d_in[17], (const float*)d_in[18],
        mem, out);

    dec_kernel<<<B_, 64, 0, stream>>>(
        mem,
        (const float*)d_in[19], (const float*)d_in[20],
        (const float*)d_in[21], (const float*)d_in[22],
        (const float*)d_in[23], (const float*)d_in[24],
        (const float*)d_in[25], (const float*)d_in[26],
        (const float*)d_in[27], (const float*)d_in[28],
        (const float*)d_in[29], (const float*)d_in[30],
        (const float*)d_in[31], (const float*)d_in[32],
        (const float*)d_in[33], (const float*)d_in[34],
        (const float*)d_in[35], (const float*)d_in[36],
        out);
}

// Round 15
// 336.145 us; speedup vs baseline: 1.0218x; 1.0218x over previous
//
#include <hip/hip_runtime.h>
#include <math.h>

#define B_ 64
#define S_ 64
#define U_ 16
#define EMB_ 10
#define D_ 34
#define DD_ 3
#define FF_ 4
#define NL_ 4

typedef float v2f __attribute__((ext_vector_type(2)));

// ---------------------------------------------------------------------------
// Kernel A: encoder — EXACT R13 (measured best: total 336.2 µs, enc ~63.7).
// pk_fma dot-products + 8-thread/row LayerNorms + LDS-free weight path
// (s_load via readfirstlane-uniform row indices). R14's FF1-in-registers
// variant regressed (+7 µs) and is reverted.
// ---------------------------------------------------------------------------
__global__ __launch_bounds__(512) void enc_kernel(
    const float* __restrict__ src, const float* __restrict__ wemb,
    const float* __restrict__ semb,
    const float* __restrict__ qkv_w, const float* __restrict__ qkv_b,
    const float* __restrict__ out_w, const float* __restrict__ out_b,
    const float* __restrict__ ln1_w, const float* __restrict__ ln1_b,
    const float* __restrict__ lin1_w, const float* __restrict__ lin1_b,
    const float* __restrict__ lin2_w, const float* __restrict__ lin2_b,
    const float* __restrict__ ln2_w, const float* __restrict__ ln2_b,
    const float* __restrict__ norm_w, const float* __restrict__ norm_b,
    const float* __restrict__ eo_w, const float* __restrict__ eo_b,
    float* __restrict__ mem, float* __restrict__ out)
{
    const int b = blockIdx.x;
    const int tid = threadIdx.x;
    const int wv_ = tid >> 6;
    const int lane = tid & 63;

    __shared__ float xs[S_][D_ + 1];
    __shared__ float tmp[S_][D_ + 1];
    __shared__ float att[S_][D_ + 1];
    __shared__ __align__(16) float qsh[2][S_][21];
    __shared__ __align__(16) float ksh[2][S_][20];
    __shared__ __align__(16) float vsh[2][S_][20];
    __shared__ float ffh[S_][5];
    __shared__ float pacc[4][128][19];

    const float rs17 = 0.24253562503633297f;
    const float negln = -logf(10000.0f) / (float)D_;

    // ---- embed + positional encoding
    #pragma unroll
    for (int rr = 0; rr < 5; ++rr) {
        int idx = tid + rr * 512;
        if (idx < S_ * D_) {
            int pos = idx / D_, d = idx % D_;
            float v;
            if (d < U_ - 2) {
                v = src[(b * S_ + pos) * U_ + d];
            } else if (d < U_ - 2 + EMB_) {
                int wi = (int)src[(b * S_ + pos) * U_ + (U_ - 2)];
                v = wemb[wi * EMB_ + (d - (U_ - 2))];
            } else {
                int si = (int)src[(b * S_ + pos) * U_ + (U_ - 1)];
                v = semb[si * EMB_ + (d - (U_ - 2 + EMB_))];
            }
            int k = d >> 1;
            float div = __expf((float)(2 * k) * negln);
            float ang = (float)b * div;
            v += (d & 1) ? __cosf(ang) : __sinf(ang);
            xs[pos][d] = v;
        }
    }
    __syncthreads();

    for (int l = 0; l < NL_; ++l) {
        const float* Wq = qkv_w + l * 3 * D_ * D_;
        const float* Bq = qkv_b + l * 3 * D_;

        // ---- qkv: lane = pos; wave owns rows r = wv_ + 8k; pk_fma dot
        {
            v2f xr2[17];
            #pragma unroll
            for (int d2 = 0; d2 < 17; ++d2) {
                v2f t; t.x = xs[lane][2 * d2]; t.y = xs[lane][2 * d2 + 1];
                xr2[d2] = t;
            }
            #pragma unroll
            for (int rb = 0; rb < 13; ++rb) {
                int r = wv_ + (rb << 3);
                if (r < 3 * D_) {
                    int ru = __builtin_amdgcn_readfirstlane(r);
                    const v2f* w2 = (const v2f*)(Wq + ru * D_);
                    v2f a2; a2.x = Bq[ru]; a2.y = 0.f;
                    #pragma unroll
                    for (int d2 = 0; d2 < 17; ++d2)
                        a2 = __builtin_elementwise_fma(xr2[d2], w2[d2], a2);
                    float acc = a2.x + a2.y;
                    if (ru < D_)          { int h = (ru >= 17), dd = ru - h * 17; qsh[h][lane][dd] = acc; }
                    else if (ru < 2 * D_) { int rr2 = ru - D_;     int h = (rr2 >= 17), dd = rr2 - h * 17; ksh[h][lane][dd] = acc; }
                    else                  { int rr2 = ru - 2 * D_; int h = (rr2 >= 17), dd = rr2 - h * 17; vsh[h][lane][dd] = acc; }
                }
            }
        }
        __syncthreads();

        // ---- attention, 4-way key-parallel
        {
            int c = tid >> 7, hq = tid & 127;
            int h = hq >> 6, qi = hq & 63;
            float qv[17], acc[17];
            #pragma unroll
            for (int d = 0; d < 17; ++d) { qv[d] = qsh[h][qi][d]; acc[d] = 0.f; }
            float ssum = 0.f;
            int j0 = c * 16;
            #pragma unroll 4
            for (int jj = 0; jj < 16; ++jj) {
                int j = j0 + jj;
                const float4* kr = (const float4*)ksh[h][j];
                const float4* vr = (const float4*)vsh[h][j];
                float4 k0 = kr[0], k1 = kr[1], k2 = kr[2], k3 = kr[3];
                float  k16 = ksh[h][j][16];
                float4 v0 = vr[0], v1 = vr[1], v2 = vr[2], v3 = vr[3];
                float  v16 = vsh[h][j][16];
                float sE = qv[0]*k0.x + qv[2]*k0.z + qv[4]*k1.x + qv[6]*k1.z +
                           qv[8]*k2.x + qv[10]*k2.z + qv[12]*k3.x + qv[14]*k3.z;
                float sO = qv[1]*k0.y + qv[3]*k0.w + qv[5]*k1.y + qv[7]*k1.w +
                           qv[9]*k2.y + qv[11]*k2.w + qv[13]*k3.y + qv[15]*k3.w;
                float sc = sE + sO + qv[16]*k16;
                float e = __expf(sc * rs17);
                ssum += e;
                acc[0] += e*v0.x;  acc[1] += e*v0.y;  acc[2] += e*v0.z;  acc[3] += e*v0.w;
                acc[4] += e*v1.x;  acc[5] += e*v1.y;  acc[6] += e*v1.z;  acc[7] += e*v1.w;
                acc[8] += e*v2.x;  acc[9] += e*v2.y;  acc[10] += e*v2.z; acc[11] += e*v2.w;
                acc[12] += e*v3.x; acc[13] += e*v3.y; acc[14] += e*v3.z; acc[15] += e*v3.w;
                acc[16] += e*v16;
            }
            #pragma unroll
            for (int d = 0; d < 17; ++d) pacc[c][hq][d] = acc[d];
            pacc[c][hq][17] = ssum;
        }
        __syncthreads();

        if (tid < 128) {
            int h = tid >> 6, qi = tid & 63;
            int off = h * 17;
            float ssum = pacc[0][tid][17] + pacc[1][tid][17] +
                         pacc[2][tid][17] + pacc[3][tid][17];
            float inv = 1.f / ssum;
            #pragma unroll
            for (int d = 0; d < 17; ++d)
                att[qi][off + d] = (pacc[0][tid][d] + pacc[1][tid][d] +
                                    pacc[2][tid][d] + pacc[3][tid][d]) * inv;
        }
        __syncthreads();

        // ---- out proj + residual (pk_fma)
        {
            v2f ar2[17];
            #pragma unroll
            for (int d2 = 0; d2 < 17; ++d2) {
                v2f t; t.x = att[lane][2 * d2]; t.y = att[lane][2 * d2 + 1];
                ar2[d2] = t;
            }
            const float* Wo = out_w + l * D_ * D_;
            const float* Bo = out_b + l * D_;
            #pragma unroll
            for (int rb = 0; rb < 5; ++rb) {
                int d = wv_ + (rb << 3);
                if (d < D_) {
                    int du = __builtin_amdgcn_readfirstlane(d);
                    const v2f* w2 = (const v2f*)(Wo + du * D_);
                    v2f a2; a2.x = Bo[du]; a2.y = 0.f;
                    #pragma unroll
                    for (int d2 = 0; d2 < 17; ++d2)
                        a2 = __builtin_elementwise_fma(ar2[d2], w2[d2], a2);
                    tmp[lane][du] = xs[lane][du] + a2.x + a2.y;
                }
            }
        }
        __syncthreads();

        // ---- LN1: 8 threads/row (all 512 active), shfl_xor(8) reduction
        {
            int row = tid >> 3, sub = tid & 7;
            float s = 0.f, sq = 0.f;
            #pragma unroll
            for (int d = sub; d < D_; d += 8) { float t = tmp[row][d]; s += t; sq = fmaf(t, t, sq); }
            #pragma unroll
            for (int m = 1; m < 8; m <<= 1) { s += __shfl_xor(s, m, 8); sq += __shfl_xor(sq, m, 8); }
            float mu = s * (1.0f / D_);
            float var = fmaf(sq, 1.0f / D_, -mu * mu);
            float rstd = rsqrtf(var + 1e-5f);
            #pragma unroll
            for (int d = sub; d < D_; d += 8)
                xs[row][d] = (tmp[row][d] - mu) * rstd * ln1_w[l * D_ + d] + ln1_b[l * D_ + d];
        }
        __syncthreads();

        // ---- FF1 (34 -> 4, relu): waves 0..3 (pk_fma)
        if (wv_ < 4) {
            int fu = __builtin_amdgcn_readfirstlane(wv_);
            const v2f* w2 = (const v2f*)(lin1_w + l * FF_ * D_ + fu * D_);
            v2f a2; a2.x = lin1_b[l * FF_ + fu]; a2.y = 0.f;
            #pragma unroll
            for (int d2 = 0; d2 < 17; ++d2) {
                v2f t; t.x = xs[lane][2 * d2]; t.y = xs[lane][2 * d2 + 1];
                a2 = __builtin_elementwise_fma(t, w2[d2], a2);
            }
            ffh[lane][fu] = fmaxf(a2.x + a2.y, 0.f);
        }
        __syncthreads();

        // ---- FF2 (4 -> 34) + residual
        {
            float h0 = ffh[lane][0], h1 = ffh[lane][1],
                  h2 = ffh[lane][2], h3 = ffh[lane][3];
            const float* W2 = lin2_w + l * D_ * FF_;
            const float* B2 = lin2_b + l * D_;
            #pragma unroll
            for (int rb = 0; rb < 5; ++rb) {
                int d = wv_ + (rb << 3);
                if (d < D_) {
                    int du = __builtin_amdgcn_readfirstlane(d);
                    const float* wrow = W2 + du * FF_;
                    float acc = fmaf(h0, wrow[0], fmaf(h1, wrow[1],
                                fmaf(h2, wrow[2], fmaf(h3, wrow[3], B2[du]))));
                    tmp[lane][du] = xs[lane][du] + acc;
                }
            }
        }
        __syncthreads();

        // ---- LN2: 8 threads/row
        {
            int row = tid >> 3, sub = tid & 7;
            float s = 0.f, sq = 0.f;
            #pragma unroll
            for (int d = sub; d < D_; d += 8) { float t = tmp[row][d]; s += t; sq = fmaf(t, t, sq); }
            #pragma unroll
            for (int m = 1; m < 8; m <<= 1) { s += __shfl_xor(s, m, 8); sq += __shfl_xor(sq, m, 8); }
            float mu = s * (1.0f / D_);
            float var = fmaf(sq, 1.0f / D_, -mu * mu);
            float rstd = rsqrtf(var + 1e-5f);
            #pragma unroll
            for (int d = sub; d < D_; d += 8)
                xs[row][d] = (tmp[row][d] - mu) * rstd * ln2_w[l * D_ + d] + ln2_b[l * D_ + d];
        }
        __syncthreads();
    }

    // ---- final LayerNorm: 8 threads/row
    {
        int row = tid >> 3, sub = tid & 7;
        float s = 0.f, sq = 0.f;
        #pragma unroll
        for (int d = sub; d < D_; d += 8) { float t = xs[row][d]; s += t; sq = fmaf(t, t, sq); }
        #pragma unroll
        for (int m = 1; m < 8; m <<= 1) { s += __shfl_xor(s, m, 8); sq += __shfl_xor(sq, m, 8); }
        float mu = s * (1.0f / D_);
        float var = fmaf(sq, 1.0f / D_, -mu * mu);
        float rstd = rsqrtf(var + 1e-5f);
        #pragma unroll
        for (int d = sub; d < D_; d += 8)
            tmp[row][d] = (xs[row][d] - mu) * rstd * norm_w[d] + norm_b[d];
    }
    __syncthreads();

    // ---- memory = x @ eo_w.T + eo_b : waves 0..2 (pk_fma), reads tmp
    if (wv_ < 3) {
        int ru = __builtin_amdgcn_readfirstlane(wv_);
        const v2f* w2 = (const v2f*)(eo_w + ru * D_);
        v2f a2; a2.x = eo_b[ru]; a2.y = 0.f;
        #pragma unroll
        for (int d2 = 0; d2 < 17; ++d2) {
            v2f t; t.x = tmp[lane][2 * d2]; t.y = tmp[lane][2 * d2 + 1];
            a2 = __builtin_elementwise_fma(t, w2[d2], a2);
        }
        mem[(b * S_ + lane) * DD_ + ru] = a2.x + a2.y;
    }

    if (tid < S_) {
        out[(b * S_ + tid) * 5 + 3] = src[(b * S_ + tid) * U_ + (U_ - 2)];
        out[(b * S_ + tid) * 5 + 4] = src[(b * S_ + tid) * U_ + (U_ - 1)];
    }
}

// ---------------------------------------------------------------------------
// Kernel B: decoder — EXACT R9/R12/R13 (measured 151.6-152.5 µs). FROZEN.
// ---------------------------------------------------------------------------
#define PIN(x) asm volatile("" : "+v"(x))

template <int CTRL>
__device__ __forceinline__ float dpp_add(float v) {
    int t = __builtin_amdgcn_update_dpp(0, __float_as_int(v), CTRL, 0xf, 0xf, true);
    return v + __int_as_float(t);
}

__device__ __forceinline__ float wave_sum_l63(float v) {
    v = dpp_add<0x111>(v);
    v = dpp_add<0x112>(v);
    v = dpp_add<0x114>(v);
    v = dpp_add<0x118>(v);
    v = dpp_add<0x142>(v);
    v = dpp_add<0x143>(v);
    return v;
}

__device__ __forceinline__ float bcast63(float v) {
    return __int_as_float(__builtin_amdgcn_readlane(__float_as_int(v), 63));
}

__device__ __forceinline__ void ln3e(float z0, float z1, float z2,
                                     float w0, float w1, float w2,
                                     float b0, float b1, float b2,
                                     float& o0, float& o1, float& o2) {
    float s1 = (z0 + z1) + z2;
    float s2 = fmaf(z0, z0, fmaf(z1, z1, z2 * z2));
    float mu = s1 * (1.0f / 3.0f);
    float vpe = fmaf(s2, (1.0f / 3.0f), fmaf(-mu, mu, 1e-5f));
    float rstd = __builtin_amdgcn_rsqf(vpe);
    o0 = fmaf(z0 - mu, rstd * w0, b0);
    o1 = fmaf(z1 - mu, rstd * w1, b1);
    o2 = fmaf(z2 - mu, rstd * w2, b2);
}

__global__ __launch_bounds__(64, 1) void dec_kernel(
    const float* __restrict__ mem,
    const float* __restrict__ sa_qkv_w, const float* __restrict__ sa_qkv_b,
    const float* __restrict__ sa_out_w, const float* __restrict__ sa_out_b,
    const float* __restrict__ gln1_w, const float* __restrict__ gln1_b,
    const float* __restrict__ ca_qkv_w, const float* __restrict__ ca_qkv_b,
    const float* __restrict__ ca_out_w, const float* __restrict__ ca_out_b,
    const float* __restrict__ gln2_w, const float* __restrict__ gln2_b,
    const float* __restrict__ l1_w, const float* __restrict__ l1_b,
    const float* __restrict__ l2_w, const float* __restrict__ l2_b,
    const float* __restrict__ gln3_w, const float* __restrict__ gln3_b,
    float* __restrict__ out)
{
    const int b = blockIdx.x;
    const int lane = threadIdx.x;
    const float LOG2E = 1.4426950408889634f;
    const float rs3 = 0.5773502691896258f;
    const float QS = rs3 * LOG2E;   // score scale folded into weights, exp->exp2

    // ---- FF-tail weight stage (R5/R9 layout)
    __shared__ __align__(16) float fst[NL_][40];
    for (int t = lane; t < NL_ * 40; t += 64) {
        int l = t / 40, s = t % 40;
        float v = 0.f;
        if      (s < 12) v = l1_w[l * 12 + s];
        else if (s < 16) v = l1_b[l * 4 + (s - 12)];
        else if (s < 28) v = l2_w[l * 12 + (s - 16)];
        else if (s < 31) v = l2_b[l * 3 + (s - 28)];
        else if (s < 34) v = gln3_w[l * 3 + (s - 31)];
        else if (s < 37) v = gln3_b[l * 3 + (s - 34)];
        fst[l][s] = v;
    }
    __syncthreads();

    // ---- persistent pinned weights (R5 set, q rows scaled by QS)
    float Wsq[NL_][9][3], Bsq[NL_][9];
    float Wso[NL_][3][3], Bso[NL_][3];
    float N1w[NL_][3], N1b[NL_][3];
    float Wcq[NL_][3][3], Bcq[NL_][3];
    float Wco[NL_][3][3], Bco[NL_][3];
    float N2w[NL_][3], N2b[NL_][3];

    #pragma unroll
    for (int l = 0; l < NL_; ++l) {
        #pragma unroll
        for (int r = 0; r < 9; ++r) {
            float sc = (r < 3) ? QS : 1.0f;
            Bsq[l][r] = sa_qkv_b[l * 9 + r] * sc;
            #pragma unroll
            for (int c = 0; c < 3; ++c) Wsq[l][r][c] = sa_qkv_w[l * 27 + r * 3 + c] * sc;
        }
        #pragma unroll
        for (int r = 0; r < 3; ++r) {
            Bso[l][r] = sa_out_b[l * 3 + r];
            Bcq[l][r] = ca_qkv_b[l * 9 + r] * QS;
            Bco[l][r] = ca_out_b[l * 3 + r];
            N1w[l][r] = gln1_w[l * 3 + r];  N1b[l][r] = gln1_b[l * 3 + r];
            N2w[l][r] = gln2_w[l * 3 + r];  N2b[l][r] = gln2_b[l * 3 + r];
            #pragma unroll
            for (int c = 0; c < 3; ++c) {
                Wso[l][r][c] = sa_out_w[l * 9 + r * 3 + c];
                Wcq[l][r][c] = ca_qkv_w[l * 27 + r * 3 + c] * QS;
                Wco[l][r][c] = ca_out_w[l * 9 + r * 3 + c];
            }
        }
    }

    // ---- cross-attn K/V per lane (memory position = lane)
    float m0 = mem[(b * S_ + lane) * DD_ + 0];
    float m1 = mem[(b * S_ + lane) * DD_ + 1];
    float m2 = mem[(b * S_ + lane) * DD_ + 2];

    float ck[NL_][3], cv[NL_][3];
    #pragma unroll
    for (int l = 0; l < NL_; ++l) {
        #pragma unroll
        for (int r = 0; r < 3; ++r) {
            ck[l][r] = ca_qkv_w[l * 27 + (3 + r) * 3 + 0] * m0 +
                       ca_qkv_w[l * 27 + (3 + r) * 3 + 1] * m1 +
                       ca_qkv_w[l * 27 + (3 + r) * 3 + 2] * m2 + ca_qkv_b[l * 9 + 3 + r];
            cv[l][r] = ca_qkv_w[l * 27 + (6 + r) * 3 + 0] * m0 +
                       ca_qkv_w[l * 27 + (6 + r) * 3 + 1] * m1 +
                       ca_qkv_w[l * 27 + (6 + r) * 3 + 2] * m2 + ca_qkv_b[l * 9 + 6 + r];
        }
    }

    // ---- pin the chain-critical set (R5 set)
    #pragma unroll
    for (int l = 0; l < NL_; ++l) {
        #pragma unroll
        for (int r = 0; r < 9; ++r) {
            PIN(Bsq[l][r]);
            #pragma unroll
            for (int c = 0; c < 3; ++c) PIN(Wsq[l][r][c]);
        }
        #pragma unroll
        for (int r = 0; r < 3; ++r) {
            PIN(Bso[l][r]); PIN(Bcq[l][r]); PIN(Bco[l][r]);
            PIN(N1w[l][r]); PIN(N1b[l][r]); PIN(N2w[l][r]); PIN(N2b[l][r]);
            #pragma unroll
            for (int c = 0; c < 3; ++c) { PIN(Wso[l][r][c]); PIN(Wcq[l][r][c]); PIN(Wco[l][r][c]); }
        }
    }

    // self-attn KV cache: lane j owns position j
    float sk[NL_][3] = {{0.f}}, sv[NL_][3] = {{0.f}};

    if (lane < 3) out[(b * S_ + 0) * 5 + lane] = 0.f;

    float y0 = 0.f, y1 = 0.f, y2 = 0.f;

    for (int i = 0; i < S_ - 1; ++i) {
        float msa = (lane <= i) ? 0.f : -1.0e30f;   // causal mask, once/step
        #pragma unroll
        for (int l = 0; l < NL_; ++l) {
            // ---- FF-tail weights: LDS reads at layer top, PINned (R9 scheme)
            float wv[40];
            {
                const float4* fp = (const float4*)fst[l];
                #pragma unroll
                for (int k = 0; k < 10; ++k) {
                    float4 t4 = fp[k];
                    wv[4 * k + 0] = t4.x; wv[4 * k + 1] = t4.y;
                    wv[4 * k + 2] = t4.z; wv[4 * k + 3] = t4.w;
                }
                #pragma unroll
                for (int k = 0; k < 37; ++k) PIN(wv[k]);
            }

            // ---- causal self-attention (q pre-scaled by QS; mask in fma)
            float q[3], kn[3], vn[3];
            #pragma unroll
            for (int r = 0; r < 3; ++r) {
                q[r]  = fmaf(Wsq[l][r][0], y0, fmaf(Wsq[l][r][1], y1, fmaf(Wsq[l][r][2], y2, Bsq[l][r])));
                kn[r] = fmaf(Wsq[l][3 + r][0], y0, fmaf(Wsq[l][3 + r][1], y1, fmaf(Wsq[l][3 + r][2], y2, Bsq[l][3 + r])));
                vn[r] = fmaf(Wsq[l][6 + r][0], y0, fmaf(Wsq[l][6 + r][1], y1, fmaf(Wsq[l][6 + r][2], y2, Bsq[l][6 + r])));
            }
            if (lane == i) {
                #pragma unroll
                for (int r = 0; r < 3; ++r) { sk[l][r] = kn[r]; sv[l][r] = vn[r]; }
            }
            float sc = fmaf(q[0], sk[l][0], fmaf(q[1], sk[l][1], fmaf(q[2], sk[l][2], msa)));
            float e = __builtin_amdgcn_exp2f(sc);
            float es  = wave_sum_l63(e);
            float ev0 = wave_sum_l63(e * sv[l][0]);
            float ev1 = wave_sum_l63(e * sv[l][1]);
            float ev2 = wave_sum_l63(e * sv[l][2]);
            float inv = __builtin_amdgcn_rcpf(bcast63(es));
            float a0 = bcast63(ev0) * inv, a1 = bcast63(ev1) * inv, a2 = bcast63(ev2) * inv;
            float s0 = fmaf(Wso[l][0][0], a0, fmaf(Wso[l][0][1], a1, fmaf(Wso[l][0][2], a2, Bso[l][0])));
            float s1 = fmaf(Wso[l][1][0], a0, fmaf(Wso[l][1][1], a1, fmaf(Wso[l][1][2], a2, Bso[l][1])));
            float s2 = fmaf(Wso[l][2][0], a0, fmaf(Wso[l][2][1], a1, fmaf(Wso[l][2][2], a2, Bso[l][2])));
            ln3e(y0 + s0, y1 + s1, y2 + s2,
                 N1w[l][0], N1w[l][1], N1w[l][2], N1b[l][0], N1b[l][1], N1b[l][2],
                 y0, y1, y2);

            // ---- cross-attention (p pre-scaled by QS)
            float p0 = fmaf(Wcq[l][0][0], y0, fmaf(Wcq[l][0][1], y1, fmaf(Wcq[l][0][2], y2, Bcq[l][0])));
            float p1 = fmaf(Wcq[l][1][0], y0, fmaf(Wcq[l][1][1], y1, fmaf(Wcq[l][1][2], y2, Bcq[l][1])));
            float p2 = fmaf(Wcq[l][2][0], y0, fmaf(Wcq[l][2][1], y1, fmaf(Wcq[l][2][2], y2, Bcq[l][2])));
            float sc2 = fmaf(p0, ck[l][0], fmaf(p1, ck[l][1], p2 * ck[l][2]));
            float e2 = __builtin_amdgcn_exp2f(sc2);
            float cs  = wave_sum_l63(e2);
            float cw0 = wave_sum_l63(e2 * cv[l][0]);
            float cw1 = wave_sum_l63(e2 * cv[l][1]);
            float cw2 = wave_sum_l63(e2 * cv[l][2]);
            inv = __builtin_amdgcn_rcpf(bcast63(cs));
            a0 = bcast63(cw0) * inv; a1 = bcast63(cw1) * inv; a2 = bcast63(cw2) * inv;
            float c0 = fmaf(Wco[l][0][0], a0, fmaf(Wco[l][0][1], a1, fmaf(Wco[l][0][2], a2, Bco[l][0])));
            float c1 = fmaf(Wco[l][1][0], a0, fmaf(Wco[l][1][1], a1, fmaf(Wco[l][1][2], a2, Bco[l][1])));
            float c2 = fmaf(Wco[l][2][0], a0, fmaf(Wco[l][2][1], a1, fmaf(Wco[l][2][2], a2, Bco[l][2])));
            ln3e(y0 + c0, y1 + c1, y2 + c2,
                 N2w[l][0], N2w[l][1], N2w[l][2], N2b[l][0], N2b[l][1], N2b[l][2],
                 y0, y1, y2);

            // ---- feed-forward 3 -> 4 -> 3 (relu) from LDS-staged wv[]
            float h0 = fmaxf(fmaf(wv[0], y0, fmaf(wv[1],  y1, fmaf(wv[2],  y2, wv[12]))), 0.f);
            float h1 = fmaxf(fmaf(wv[3], y0, fmaf(wv[4],  y1, fmaf(wv[5],  y2, wv[13]))), 0.f);
            float h2 = fmaxf(fmaf(wv[6], y0, fmaf(wv[7],  y1, fmaf(wv[8],  y2, wv[14]))), 0.f);
            float h3 = fmaxf(fmaf(wv[9], y0, fmaf(wv[10], y1, fmaf(wv[11], y2, wv[15]))), 0.f);
            float f0 = fmaf(wv[16], h0, fmaf(wv[17], h1, fmaf(wv[18], h2, fmaf(wv[19], h3, wv[28]))));
            float f1 = fmaf(wv[20], h0, fmaf(wv[21], h1, fmaf(wv[22], h2, fmaf(wv[23], h3, wv[29]))));
            float f2 = fmaf(wv[24], h0, fmaf(wv[25], h1, fmaf(wv[26], h2, fmaf(wv[27], h3, wv[30]))));
            ln3e(y0 + f0, y1 + f1, y2 + f2,
                 wv[31], wv[32], wv[33], wv[34], wv[35], wv[36],
                 y0, y1, y2);
        }
        if (lane == 0) {
            out[(b * S_ + i + 1) * 5 + 0] = y0;
            out[(b * S_ + i + 1) * 5 + 1] = y1;
            out[(b * S_ + i + 1) * 5 + 2] = y2;
        }
    }
}

// ---------------------------------------------------------------------------
extern "C" void kernel_launch(void* const* d_in, const int* in_sizes, int n_in,
                              void* d_out, int out_size, void* d_ws, size_t ws_size,
                              hipStream_t stream) {
    const float* src  = (const float*)d_in[0];
    const float* wemb = (const float*)d_in[1];
    const float* semb = (const float*)d_in[2];

    float* mem = (float*)d_ws;           // [B,S,3] scratch
    float* out = (float*)d_out;          // [B,S,5]

    enc_kernel<<<B_, 512, 0, stream>>>(
        src, wemb, semb,
        (const float*)d_in[3],  (const float*)d_in[4],
        (const float*)d_in[5],  (const float*)d_in[6],
        (const float*)d_in[7],  (const float*)d_in[8],
        (const float*)d_in[9],  (const float*)d_in[10],
        (const float*)d_in[11], (const float*)d_in[12],
        (const float*)d_in[13], (const float*)d_in[14],
        (const float*)d_in[15], (const float*)d_in[16],
        (const float*)d_in[17], (const float*)d_in[18],
        mem, out);

    dec_kernel<<<B_, 64, 0, stream>>>(
        mem,
        (const float*)d_in[19], (const float*)d_in[20],
        (const float*)d_in[21], (const float*)d_in[22],
        (const float*)d_in[23], (const float*)d_in[24],
        (const float*)d_in[25], (const float*)d_in[26],
        (const float*)d_in[27], (const float*)d_in[28],
        (const float*)d_in[29], (const float*)d_in[30],
        (const float*)d_in[31], (const float*)d_in[32],
        (const float*)d_in[33], (const float*)d_in[34],
        (const float*)d_in[35], (const float*)d_in[36],
        out);
}